// Round 1
// baseline (3086.069 us; speedup 1.0000x reference)
//
#include <hip/hip_runtime.h>
#include <math.h>

#define N_NODES 50000
#define N_EDGES 800000
#define IN_FT   512
#define H_FT    256
#define OUT_FT  40

// ---------------- GEMM1: sup1[M,256] = x[M,512] @ W1[512,256] + b1 ----------
// 64x64 tile, 256 threads, 4x4 per thread, LDS staged (transposed A).
__global__ __launch_bounds__(256) void gemm1_k(const float* __restrict__ A,
                                               const float* __restrict__ B,
                                               const float* __restrict__ bias,
                                               float* __restrict__ C) {
    __shared__ float As[16][68];   // [k][m]
    __shared__ float Bs[16][68];   // [k][n]
    const int bm = blockIdx.x * 64;
    const int bn = blockIdx.y * 64;
    const int t  = threadIdx.x;
    const int tx = t & 15;         // n-group
    const int ty = t >> 4;         // m-group
    const int lrow = t >> 2;       // 0..63 (A row within tile)
    const int lkq  = t & 3;        // 0..3  (A k-quarter)
    float acc[4][4] = {};

    for (int k0 = 0; k0 < IN_FT; k0 += 16) {
        // fetch to regs
        float4 av = make_float4(0.f, 0.f, 0.f, 0.f);
        const int am = bm + lrow;
        if (am < N_NODES)
            av = *(const float4*)(A + (size_t)am * IN_FT + k0 + lkq * 4);
        const int  bk = k0 + (t >> 4);
        float4 bv = *(const float4*)(B + (size_t)bk * H_FT + bn + (t & 15) * 4);

        __syncthreads();           // previous-iter LDS reads done
        As[lkq * 4 + 0][lrow] = av.x;
        As[lkq * 4 + 1][lrow] = av.y;
        As[lkq * 4 + 2][lrow] = av.z;
        As[lkq * 4 + 3][lrow] = av.w;
        *(float4*)&Bs[t >> 4][(t & 15) * 4] = bv;
        __syncthreads();

        #pragma unroll
        for (int k = 0; k < 16; ++k) {
            float a0 = As[k][ty * 4 + 0], a1 = As[k][ty * 4 + 1];
            float a2 = As[k][ty * 4 + 2], a3 = As[k][ty * 4 + 3];
            float b0 = Bs[k][tx * 4 + 0], b1 = Bs[k][tx * 4 + 1];
            float b2 = Bs[k][tx * 4 + 2], b3 = Bs[k][tx * 4 + 3];
            acc[0][0] += a0 * b0; acc[0][1] += a0 * b1; acc[0][2] += a0 * b2; acc[0][3] += a0 * b3;
            acc[1][0] += a1 * b0; acc[1][1] += a1 * b1; acc[1][2] += a1 * b2; acc[1][3] += a1 * b3;
            acc[2][0] += a2 * b0; acc[2][1] += a2 * b1; acc[2][2] += a2 * b2; acc[2][3] += a2 * b3;
            acc[3][0] += a3 * b0; acc[3][1] += a3 * b1; acc[3][2] += a3 * b2; acc[3][3] += a3 * b3;
        }
    }

    #pragma unroll
    for (int i = 0; i < 4; ++i) {
        const int m = bm + ty * 4 + i;
        if (m >= N_NODES) continue;
        const int n = bn + tx * 4;
        float4 o;
        o.x = acc[i][0] + bias[n + 0];
        o.y = acc[i][1] + bias[n + 1];
        o.z = acc[i][2] + bias[n + 2];
        o.w = acc[i][3] + bias[n + 3];
        *(float4*)(C + (size_t)m * H_FT + n) = o;
    }
}

// ---------------- SpMM1: hacc[dst] += sup1[src] * w  (atomic) ---------------
// One wave per edge (64 lanes x float4 = 256 features). 4 edges / block.
__global__ __launch_bounds__(256) void spmm1_k(const int* __restrict__ src,
                                               const int* __restrict__ dst,
                                               const float* __restrict__ w,
                                               const float* __restrict__ sup,
                                               float* __restrict__ hacc) {
    const int e = blockIdx.x * 4 + (threadIdx.x >> 6);
    if (e >= N_EDGES) return;
    const int lane = threadIdx.x & 63;
    const int s = src[e];
    const int d = dst[e];
    const float ww = w[e];
    float4 v = *(const float4*)(sup + (size_t)s * H_FT + lane * 4);
    float* o = hacc + (size_t)d * H_FT + lane * 4;
    unsafeAtomicAdd(o + 0, v.x * ww);
    unsafeAtomicAdd(o + 1, v.y * ww);
    unsafeAtomicAdd(o + 2, v.z * ww);
    unsafeAtomicAdd(o + 3, v.w * ww);
}

// ---------------- GEMM2: sup2[M,40] = relu(hacc)[M,256] @ W2[256,40] + b2 ---
// W2 staged whole in LDS (40KB); one wave per row; lanes 0..39 produce outputs.
__global__ __launch_bounds__(256) void gemm2_k(const float* __restrict__ h,
                                               const float* __restrict__ W2,
                                               const float* __restrict__ b2,
                                               float* __restrict__ sup2) {
    __shared__ float w2s[H_FT * OUT_FT];   // 40KB
    __shared__ float rows[4][H_FT];        // 4KB
    const int t = threadIdx.x;
    for (int i = t; i < H_FT * OUT_FT; i += 256) w2s[i] = W2[i];
    const int wid = t >> 6, lane = t & 63;
    const int m = blockIdx.x * 4 + wid;
    float4 hv = *(const float4*)(h + (size_t)m * H_FT + lane * 4);
    rows[wid][lane * 4 + 0] = fmaxf(hv.x, 0.f);
    rows[wid][lane * 4 + 1] = fmaxf(hv.y, 0.f);
    rows[wid][lane * 4 + 2] = fmaxf(hv.z, 0.f);
    rows[wid][lane * 4 + 3] = fmaxf(hv.w, 0.f);
    __syncthreads();
    if (lane < OUT_FT) {
        float acc = b2[lane];
        #pragma unroll 8
        for (int k = 0; k < H_FT; ++k)
            acc += rows[wid][k] * w2s[k * OUT_FT + lane];
        sup2[(size_t)m * OUT_FT + lane] = acc;
    }
}

// ---------------- SpMM2: out[dst] += sup2[src] * w  (atomic) ----------------
__global__ __launch_bounds__(256) void spmm2_k(const int* __restrict__ src,
                                               const int* __restrict__ dst,
                                               const float* __restrict__ w,
                                               const float* __restrict__ sup2,
                                               float* __restrict__ out) {
    const long long idx = (long long)blockIdx.x * 256 + threadIdx.x;
    if (idx >= (long long)N_EDGES * OUT_FT) return;
    const int e = (int)(idx / OUT_FT);
    const int f = (int)(idx % OUT_FT);
    const int s = src[e];
    const int d = dst[e];
    const float v = sup2[(size_t)s * OUT_FT + f] * w[e];
    unsafeAtomicAdd(out + (size_t)d * OUT_FT + f, v);
}

// ---------------- log_softmax(relu(out)) rows of 40, in place ---------------
__global__ __launch_bounds__(256) void lsm_k(float* __restrict__ out) {
    const int t = threadIdx.x, wid = t >> 6, lane = t & 63;
    const int m = blockIdx.x * 4 + wid;
    float r = 0.f, v = -INFINITY;
    if (lane < OUT_FT) {
        r = fmaxf(out[(size_t)m * OUT_FT + lane], 0.f);
        v = r;
    }
    #pragma unroll
    for (int o = 32; o; o >>= 1) v = fmaxf(v, __shfl_xor(v, o));
    float e = (lane < OUT_FT) ? expf(r - v) : 0.f;
    #pragma unroll
    for (int o = 32; o; o >>= 1) e += __shfl_xor(e, o);
    if (lane < OUT_FT)
        out[(size_t)m * OUT_FT + lane] = r - v - logf(e);
}

extern "C" void kernel_launch(void* const* d_in, const int* in_sizes, int n_in,
                              void* d_out, int out_size, void* d_ws, size_t ws_size,
                              hipStream_t stream) {
    const float* x    = (const float*)d_in[0];
    const int*   esrc = (const int*)  d_in[1];
    const int*   edst = (const int*)  d_in[2];
    const float* ew   = (const float*)d_in[3];
    const float* W1   = (const float*)d_in[4];
    const float* b1   = (const float*)d_in[5];
    const float* W2   = (const float*)d_in[6];
    const float* b2   = (const float*)d_in[7];
    float* out = (float*)d_out;

    float* sup1 = (float*)d_ws;                              // 50000*256 f32
    float* hacc = sup1 + (size_t)N_NODES * H_FT;             // 50000*256 f32
    float* sup2 = hacc + (size_t)N_NODES * H_FT;             // 50000*40  f32

    hipMemsetAsync(hacc, 0, (size_t)N_NODES * H_FT * sizeof(float), stream);
    hipMemsetAsync(out,  0, (size_t)N_NODES * OUT_FT * sizeof(float), stream);

    gemm1_k<<<dim3((N_NODES + 63) / 64, H_FT / 64), 256, 0, stream>>>(x, W1, b1, sup1);
    spmm1_k<<<(N_EDGES + 3) / 4, 256, 0, stream>>>(esrc, edst, ew, sup1, hacc);
    gemm2_k<<<N_NODES / 4, 256, 0, stream>>>(hacc, W2, b2, sup2);
    spmm2_k<<<(N_EDGES * OUT_FT + 255) / 256, 256, 0, stream>>>(esrc, edst, ew, sup2, out);
    lsm_k<<<N_NODES / 4, 256, 0, stream>>>(out);
}

// Round 2
// 673.365 us; speedup vs baseline: 4.5831x; 4.5831x over previous
//
#include <hip/hip_runtime.h>
#include <math.h>

#define N_NODES 50000
#define N_EDGES 800000
#define IN_FT   512
#define H_FT    256
#define OUT_FT  40

// ================= CSR build (dst-sorted) ===================================
__global__ __launch_bounds__(256) void count_k(const int* __restrict__ dst,
                                               int* __restrict__ deg) {
    const int e = blockIdx.x * 256 + threadIdx.x;
    if (e < N_EDGES) atomicAdd(&deg[dst[e]], 1);
}

// single-block 1024-thread scan over 50000 degrees -> off[0..N], cursor copy
__global__ __launch_bounds__(1024) void scan_k(const int* __restrict__ deg,
                                               int* __restrict__ off,
                                               int* __restrict__ cursor) {
    __shared__ int part[1024];
    const int t = threadIdx.x;
    const int chunk = (N_NODES + 1023) / 1024;      // 49
    const int s0 = t * chunk;
    int sum = 0;
    for (int i = 0; i < chunk; ++i) {
        const int idx = s0 + i;
        if (idx < N_NODES) sum += deg[idx];
    }
    part[t] = sum;
    __syncthreads();
    for (int ofs = 1; ofs < 1024; ofs <<= 1) {      // Hillis-Steele inclusive
        int v = (t >= ofs) ? part[t - ofs] : 0;
        __syncthreads();
        part[t] += v;
        __syncthreads();
    }
    int run = (t == 0) ? 0 : part[t - 1];           // exclusive prefix
    for (int i = 0; i < chunk; ++i) {
        const int idx = s0 + i;
        if (idx < N_NODES) {
            off[idx] = run;
            cursor[idx] = run;
            run += deg[idx];
        }
    }
    if (t == 1023) off[N_NODES] = part[1023];
}

__global__ __launch_bounds__(256) void scatter_k(const int* __restrict__ src,
                                                 const int* __restrict__ dst,
                                                 const float* __restrict__ w,
                                                 int* __restrict__ cursor,
                                                 int2* __restrict__ pk) {
    const int e = blockIdx.x * 256 + threadIdx.x;
    if (e < N_EDGES) {
        const int d = dst[e];
        const int pos = atomicAdd(&cursor[d], 1);
        pk[pos] = make_int2(src[e], __float_as_int(w[e]));
    }
}

// ================= GEMM1: sup1[M,256] = x[M,512] @ W1 + b1 ==================
__global__ __launch_bounds__(256) void gemm1_k(const float* __restrict__ A,
                                               const float* __restrict__ B,
                                               const float* __restrict__ bias,
                                               float* __restrict__ C) {
    __shared__ float As[16][68];   // [k][m]
    __shared__ float Bs[16][68];   // [k][n]
    const int bm = blockIdx.x * 64;
    const int bn = blockIdx.y * 64;
    const int t  = threadIdx.x;
    const int tx = t & 15;
    const int ty = t >> 4;
    const int lrow = t >> 2;
    const int lkq  = t & 3;
    float acc[4][4] = {};

    for (int k0 = 0; k0 < IN_FT; k0 += 16) {
        float4 av = make_float4(0.f, 0.f, 0.f, 0.f);
        const int am = bm + lrow;
        if (am < N_NODES)
            av = *(const float4*)(A + (size_t)am * IN_FT + k0 + lkq * 4);
        const int bk = k0 + (t >> 4);
        float4 bv = *(const float4*)(B + (size_t)bk * H_FT + bn + (t & 15) * 4);

        __syncthreads();
        As[lkq * 4 + 0][lrow] = av.x;
        As[lkq * 4 + 1][lrow] = av.y;
        As[lkq * 4 + 2][lrow] = av.z;
        As[lkq * 4 + 3][lrow] = av.w;
        *(float4*)&Bs[t >> 4][(t & 15) * 4] = bv;
        __syncthreads();

        #pragma unroll
        for (int k = 0; k < 16; ++k) {
            float a0 = As[k][ty * 4 + 0], a1 = As[k][ty * 4 + 1];
            float a2 = As[k][ty * 4 + 2], a3 = As[k][ty * 4 + 3];
            float b0 = Bs[k][tx * 4 + 0], b1 = Bs[k][tx * 4 + 1];
            float b2 = Bs[k][tx * 4 + 2], b3 = Bs[k][tx * 4 + 3];
            acc[0][0] += a0 * b0; acc[0][1] += a0 * b1; acc[0][2] += a0 * b2; acc[0][3] += a0 * b3;
            acc[1][0] += a1 * b0; acc[1][1] += a1 * b1; acc[1][2] += a1 * b2; acc[1][3] += a1 * b3;
            acc[2][0] += a2 * b0; acc[2][1] += a2 * b1; acc[2][2] += a2 * b2; acc[2][3] += a2 * b3;
            acc[3][0] += a3 * b0; acc[3][1] += a3 * b1; acc[3][2] += a3 * b2; acc[3][3] += a3 * b3;
        }
    }

    #pragma unroll
    for (int i = 0; i < 4; ++i) {
        const int m = bm + ty * 4 + i;
        if (m >= N_NODES) continue;
        const int n = bn + tx * 4;
        float4 o;
        o.x = acc[i][0] + bias[n + 0];
        o.y = acc[i][1] + bias[n + 1];
        o.z = acc[i][2] + bias[n + 2];
        o.w = acc[i][3] + bias[n + 3];
        *(float4*)(C + (size_t)m * H_FT + n) = o;
    }
}

// ========== SpMM1 gather: hout[m] = relu(sum_e w_e * sup1[src_e]) ===========
// One wave per dst node; 64 lanes x float4 = 256 features.
__global__ __launch_bounds__(256) void spmm1_g(const int* __restrict__ off,
                                               const int2* __restrict__ pk,
                                               const float* __restrict__ sup,
                                               float* __restrict__ hout) {
    const int m = blockIdx.x * 4 + (threadIdx.x >> 6);
    if (m >= N_NODES) return;
    const int lane = threadIdx.x & 63;
    float4 acc = make_float4(0.f, 0.f, 0.f, 0.f);
    const int b = off[m], e = off[m + 1];
    for (int i = b; i < e; ++i) {
        const int2 p = pk[i];
        const float w = __int_as_float(p.y);
        const float4 v = *(const float4*)(sup + (size_t)p.x * H_FT + lane * 4);
        acc.x += v.x * w; acc.y += v.y * w; acc.z += v.z * w; acc.w += v.w * w;
    }
    float4 r;
    r.x = fmaxf(acc.x, 0.f); r.y = fmaxf(acc.y, 0.f);
    r.z = fmaxf(acc.z, 0.f); r.w = fmaxf(acc.w, 0.f);
    *(float4*)(hout + (size_t)m * H_FT + lane * 4) = r;
}

// ======= GEMM2: sup2[M,40] = h[M,256] @ W2[256,40] + b2 (h pre-relu'd) ======
__global__ __launch_bounds__(256) void gemm2_k(const float* __restrict__ h,
                                               const float* __restrict__ W2,
                                               const float* __restrict__ b2,
                                               float* __restrict__ sup2) {
    __shared__ float w2s[H_FT * OUT_FT];   // 40KB
    __shared__ float rows[4][H_FT];        // 4KB
    const int t = threadIdx.x;
    for (int i = t; i < H_FT * OUT_FT; i += 256) w2s[i] = W2[i];
    const int wid = t >> 6, lane = t & 63;
    const int m = blockIdx.x * 4 + wid;
    float4 hv = *(const float4*)(h + (size_t)m * H_FT + lane * 4);
    rows[wid][lane * 4 + 0] = hv.x;
    rows[wid][lane * 4 + 1] = hv.y;
    rows[wid][lane * 4 + 2] = hv.z;
    rows[wid][lane * 4 + 3] = hv.w;
    __syncthreads();
    if (lane < OUT_FT) {
        float acc = b2[lane];
        #pragma unroll 8
        for (int k = 0; k < H_FT; ++k)
            acc += rows[wid][k] * w2s[k * OUT_FT + lane];
        sup2[(size_t)m * OUT_FT + lane] = acc;
    }
}

// ===== SpMM2 + relu + log_softmax fused: out[m] = lsm(relu(gather)) =========
__global__ __launch_bounds__(256) void spmm2lsm_k(const int* __restrict__ off,
                                                  const int2* __restrict__ pk,
                                                  const float* __restrict__ sup2,
                                                  float* __restrict__ out) {
    const int m = blockIdx.x * 4 + (threadIdx.x >> 6);
    if (m >= N_NODES) return;
    const int lane = threadIdx.x & 63;
    const int f = (lane < OUT_FT) ? lane : 0;      // clamp, mask at end
    float acc = 0.f;
    const int b = off[m], e = off[m + 1];
    for (int i = b; i < e; ++i) {
        const int2 p = pk[i];
        acc += sup2[(size_t)p.x * OUT_FT + f] * __int_as_float(p.y);
    }
    const bool act = (lane < OUT_FT);
    float r = act ? fmaxf(acc, 0.f) : 0.f;
    float mx = act ? r : -INFINITY;
    #pragma unroll
    for (int o = 32; o; o >>= 1) mx = fmaxf(mx, __shfl_xor(mx, o));
    float ex = act ? expf(r - mx) : 0.f;
    #pragma unroll
    for (int o = 32; o; o >>= 1) ex += __shfl_xor(ex, o);
    if (act) out[(size_t)m * OUT_FT + lane] = r - mx - logf(ex);
}

extern "C" void kernel_launch(void* const* d_in, const int* in_sizes, int n_in,
                              void* d_out, int out_size, void* d_ws, size_t ws_size,
                              hipStream_t stream) {
    const float* x    = (const float*)d_in[0];
    const int*   esrc = (const int*)  d_in[1];
    const int*   edst = (const int*)  d_in[2];
    const float* ew   = (const float*)d_in[3];
    const float* W1   = (const float*)d_in[4];
    const float* b1   = (const float*)d_in[5];
    const float* W2   = (const float*)d_in[6];
    const float* b2   = (const float*)d_in[7];
    float* out = (float*)d_out;

    // ---- workspace layout (bytes, 16B aligned) ----
    char* p = (char*)d_ws;
    int*  deg    = (int*)p;               p += ((N_NODES     * 4 + 255) & ~255);
    int*  off    = (int*)p;               p += (((N_NODES+1) * 4 + 255) & ~255);
    int*  cursor = (int*)p;               p += ((N_NODES     * 4 + 255) & ~255);
    int2* pk     = (int2*)p;              p += ((size_t)N_EDGES * 8);
    float* sup1  = (float*)p;             p += (size_t)N_NODES * H_FT * 4;
    float* hacc  = (float*)p;             p += (size_t)N_NODES * H_FT * 4;
    float* sup2  = sup1;                  // alias: sup1 dead after spmm1_g

    hipMemsetAsync(deg, 0, (size_t)N_NODES * 4, stream);

    // CSR build
    count_k  <<<(N_EDGES + 255) / 256, 256, 0, stream>>>(edst, deg);
    scan_k   <<<1, 1024, 0, stream>>>(deg, off, cursor);
    scatter_k<<<(N_EDGES + 255) / 256, 256, 0, stream>>>(esrc, edst, ew, cursor, pk);

    // layer 1
    gemm1_k<<<dim3((N_NODES + 63) / 64, H_FT / 64), 256, 0, stream>>>(x, W1, b1, sup1);
    spmm1_g<<<(N_NODES + 3) / 4, 256, 0, stream>>>(off, pk, sup1, hacc);

    // layer 2 (+ fused relu + log_softmax)
    gemm2_k   <<<N_NODES / 4, 256, 0, stream>>>(hacc, W2, b2, sup2);
    spmm2lsm_k<<<(N_NODES + 3) / 4, 256, 0, stream>>>(off, pk, sup2, out);
}

// Round 3
// 535.678 us; speedup vs baseline: 5.7611x; 1.2570x over previous
//
#include <hip/hip_runtime.h>
#include <math.h>

#define N_NODES 50000
#define N_EDGES 800000
#define IN_FT   512
#define H_FT    256
#define OUT_FT  40

typedef __attribute__((ext_vector_type(8))) short short8;   // 8 x bf16 (4 VGPR)
typedef __attribute__((ext_vector_type(4))) float f32x4;

__device__ __forceinline__ unsigned short f2b(float f) {    // f32 -> bf16 RNE
    unsigned int u = __float_as_uint(f);
    unsigned int r = (u + 0x7FFFu + ((u >> 16) & 1u)) >> 16;
    return (unsigned short)r;
}
__device__ __forceinline__ float b2f(unsigned short h) {
    return __uint_as_float(((unsigned int)h) << 16);
}

// ================= CSR build (dst-sorted) ===================================
__global__ __launch_bounds__(256) void count_k(const int* __restrict__ dst,
                                               int* __restrict__ deg) {
    const int e = blockIdx.x * 256 + threadIdx.x;
    if (e < N_EDGES) atomicAdd(&deg[dst[e]], 1);
}

__global__ __launch_bounds__(1024) void scan_k(const int* __restrict__ deg,
                                               int* __restrict__ off,
                                               int* __restrict__ cursor) {
    __shared__ int part[1024];
    const int t = threadIdx.x;
    const int chunk = (N_NODES + 1023) / 1024;
    const int s0 = t * chunk;
    int sum = 0;
    for (int i = 0; i < chunk; ++i) {
        const int idx = s0 + i;
        if (idx < N_NODES) sum += deg[idx];
    }
    part[t] = sum;
    __syncthreads();
    for (int ofs = 1; ofs < 1024; ofs <<= 1) {
        int v = (t >= ofs) ? part[t - ofs] : 0;
        __syncthreads();
        part[t] += v;
        __syncthreads();
    }
    int run = (t == 0) ? 0 : part[t - 1];
    for (int i = 0; i < chunk; ++i) {
        const int idx = s0 + i;
        if (idx < N_NODES) {
            off[idx] = run;
            cursor[idx] = run;
            run += deg[idx];
        }
    }
    if (t == 1023) off[N_NODES] = part[1023];
}

__global__ __launch_bounds__(256) void scatter_k(const int* __restrict__ src,
                                                 const int* __restrict__ dst,
                                                 const float* __restrict__ w,
                                                 int* __restrict__ cursor,
                                                 int2* __restrict__ pk) {
    const int e = blockIdx.x * 256 + threadIdx.x;
    if (e < N_EDGES) {
        const int d = dst[e];
        const int pos = atomicAdd(&cursor[d], 1);
        pk[pos] = make_int2(src[e], __float_as_int(w[e]));
    }
}

// ========== W1 [512][256] f32  ->  W1T [256][512] bf16 ======================
__global__ __launch_bounds__(256) void cvtw1t_k(const float* __restrict__ W1,
                                                unsigned short* __restrict__ W1T) {
    __shared__ float tile[64][65];
    const int k0 = blockIdx.x * 64;          // 8 blocks
    const int n0 = blockIdx.y * 64;          // 4 blocks
    const int t = threadIdx.x;
    const int r = t >> 2, cg = t & 3;
    #pragma unroll
    for (int i = 0; i < 4; ++i) {
        float4 v = *(const float4*)(W1 + (size_t)(k0 + r) * H_FT + n0 + cg * 16 + i * 4);
        tile[r][cg * 16 + i * 4 + 0] = v.x;
        tile[r][cg * 16 + i * 4 + 1] = v.y;
        tile[r][cg * 16 + i * 4 + 2] = v.z;
        tile[r][cg * 16 + i * 4 + 3] = v.w;
    }
    __syncthreads();
    unsigned short o[16];
    #pragma unroll
    for (int i = 0; i < 16; ++i) o[i] = f2b(tile[cg * 16 + i][r]);
    unsigned short* dst = W1T + (size_t)(n0 + r) * IN_FT + k0 + cg * 16;
    *(short8*)(dst + 0) = *(short8*)&o[0];
    *(short8*)(dst + 8) = *(short8*)&o[8];
}

// ================= GEMM1 (MFMA bf16): sup1[M,256] = x @ W1 + b1 =============
// BM=64, BN=256 (full), BK=64. 256 threads = 4 waves, wave w owns cols w*64..
__global__ __launch_bounds__(256) void gemm1_mfma(const float* __restrict__ X,
                                                  const unsigned short* __restrict__ W1T,
                                                  const float* __restrict__ bias,
                                                  unsigned short* __restrict__ C) {
    __shared__ unsigned short As[64][72];    // 18KB, +16B row pad (2-way max)
    const int t    = threadIdx.x;
    const int lane = t & 63;
    const int wid  = t >> 6;
    const int m0   = blockIdx.x * 64;
    const int srow = t >> 2;                 // staging: 4 threads / row
    const int scg  = t & 3;                  // 16-col group
    const int arow = m0 + srow;
    const bool aval = arow < N_NODES;
    const int fr = lane & 15;                // fragment row/col
    const int fq = lane >> 4;                // k-oct / out row group

    f32x4 acc[4][4] = {};                    // [mi][ni]

    const float* xp = X + (size_t)arow * IN_FT + scg * 16;
    const unsigned short* bp = W1T + (size_t)(wid * 64 + fr) * IN_FT + fq * 8;

    for (int k0 = 0; k0 < IN_FT; k0 += 64) {
        float4 v0, v1, v2, v3;
        if (aval) {
            v0 = *(const float4*)(xp + k0 + 0);
            v1 = *(const float4*)(xp + k0 + 4);
            v2 = *(const float4*)(xp + k0 + 8);
            v3 = *(const float4*)(xp + k0 + 12);
        } else {
            v0 = v1 = v2 = v3 = make_float4(0.f, 0.f, 0.f, 0.f);
        }
        unsigned short h[16];
        h[0]=f2b(v0.x); h[1]=f2b(v0.y); h[2]=f2b(v0.z); h[3]=f2b(v0.w);
        h[4]=f2b(v1.x); h[5]=f2b(v1.y); h[6]=f2b(v1.z); h[7]=f2b(v1.w);
        h[8]=f2b(v2.x); h[9]=f2b(v2.y); h[10]=f2b(v2.z); h[11]=f2b(v2.w);
        h[12]=f2b(v3.x); h[13]=f2b(v3.y); h[14]=f2b(v3.z); h[15]=f2b(v3.w);

        __syncthreads();                     // prev-iter frag reads done
        *(short8*)&As[srow][scg * 16 + 0] = *(short8*)&h[0];
        *(short8*)&As[srow][scg * 16 + 8] = *(short8*)&h[8];
        __syncthreads();

        #pragma unroll
        for (int ks = 0; ks < 2; ++ks) {
            short8 a[4], b[4];
            #pragma unroll
            for (int mi = 0; mi < 4; ++mi)
                a[mi] = *(const short8*)&As[mi * 16 + fr][ks * 32 + fq * 8];
            #pragma unroll
            for (int ni = 0; ni < 4; ++ni)
                b[ni] = *(const short8*)(bp + (size_t)ni * 16 * IN_FT + k0 + ks * 32);
            #pragma unroll
            for (int mi = 0; mi < 4; ++mi)
                #pragma unroll
                for (int ni = 0; ni < 4; ++ni)
                    acc[mi][ni] = __builtin_amdgcn_mfma_f32_16x16x32_bf16(
                        a[mi], b[ni], acc[mi][ni], 0, 0, 0);
        }
    }

    // epilogue: + bias, -> bf16
    #pragma unroll
    for (int ni = 0; ni < 4; ++ni) {
        const int col = wid * 64 + ni * 16 + fr;
        const float bv = bias[col];
        #pragma unroll
        for (int mi = 0; mi < 4; ++mi) {
            #pragma unroll
            for (int j = 0; j < 4; ++j) {
                const int row = m0 + mi * 16 + fq * 4 + j;
                if (row < N_NODES)
                    C[(size_t)row * H_FT + col] = f2b(acc[mi][ni][j] + bv);
            }
        }
    }
}

// ========== SpMM1 gather (bf16): h[m] = relu(sum w_e * sup1[src_e]) =========
__global__ __launch_bounds__(256) void spmm1_g(const int* __restrict__ off,
                                               const int2* __restrict__ pk,
                                               const unsigned short* __restrict__ sup,
                                               unsigned short* __restrict__ hout) {
    const int m = blockIdx.x * 4 + (threadIdx.x >> 6);
    if (m >= N_NODES) return;
    const int lane = threadIdx.x & 63;
    float a0 = 0.f, a1 = 0.f, a2 = 0.f, a3 = 0.f;
    const int b = off[m], e = off[m + 1];
    for (int i = b; i < e; ++i) {
        const int2 p = pk[i];
        const float w = __int_as_float(p.y);
        const ushort4 v = *(const ushort4*)(sup + (size_t)p.x * H_FT + lane * 4);
        a0 += b2f(v.x) * w; a1 += b2f(v.y) * w;
        a2 += b2f(v.z) * w; a3 += b2f(v.w) * w;
    }
    ushort4 r;
    r.x = f2b(fmaxf(a0, 0.f)); r.y = f2b(fmaxf(a1, 0.f));
    r.z = f2b(fmaxf(a2, 0.f)); r.w = f2b(fmaxf(a3, 0.f));
    *(ushort4*)(hout + (size_t)m * H_FT + lane * 4) = r;
}

// ======= GEMM2: sup2[M,40] = h[M,256] @ W2[256,40] + b2 (h bf16) ============
__global__ __launch_bounds__(256) void gemm2_k(const unsigned short* __restrict__ h,
                                               const float* __restrict__ W2,
                                               const float* __restrict__ b2,
                                               float* __restrict__ sup2) {
    __shared__ float w2s[H_FT * OUT_FT];   // 40KB
    __shared__ float rows[4][H_FT];        // 4KB
    const int t = threadIdx.x;
    for (int i = t; i < H_FT * OUT_FT; i += 256) w2s[i] = W2[i];
    const int wid = t >> 6, lane = t & 63;
    const int m = blockIdx.x * 4 + wid;
    const ushort4 hv = *(const ushort4*)(h + (size_t)m * H_FT + lane * 4);
    rows[wid][lane * 4 + 0] = b2f(hv.x);
    rows[wid][lane * 4 + 1] = b2f(hv.y);
    rows[wid][lane * 4 + 2] = b2f(hv.z);
    rows[wid][lane * 4 + 3] = b2f(hv.w);
    __syncthreads();
    if (lane < OUT_FT) {
        float acc = b2[lane];
        #pragma unroll 8
        for (int k = 0; k < H_FT; ++k)
            acc += rows[wid][k] * w2s[k * OUT_FT + lane];
        sup2[(size_t)m * OUT_FT + lane] = acc;
    }
}

// ===== SpMM2 + relu + log_softmax fused =====================================
__global__ __launch_bounds__(256) void spmm2lsm_k(const int* __restrict__ off,
                                                  const int2* __restrict__ pk,
                                                  const float* __restrict__ sup2,
                                                  float* __restrict__ out) {
    const int m = blockIdx.x * 4 + (threadIdx.x >> 6);
    if (m >= N_NODES) return;
    const int lane = threadIdx.x & 63;
    const int f = (lane < OUT_FT) ? lane : 0;
    float acc = 0.f;
    const int b = off[m], e = off[m + 1];
    for (int i = b; i < e; ++i) {
        const int2 p = pk[i];
        acc += sup2[(size_t)p.x * OUT_FT + f] * __int_as_float(p.y);
    }
    const bool act = (lane < OUT_FT);
    float r = act ? fmaxf(acc, 0.f) : 0.f;
    float mx = act ? r : -INFINITY;
    #pragma unroll
    for (int o = 32; o; o >>= 1) mx = fmaxf(mx, __shfl_xor(mx, o));
    float ex = act ? expf(r - mx) : 0.f;
    #pragma unroll
    for (int o = 32; o; o >>= 1) ex += __shfl_xor(ex, o);
    if (act) out[(size_t)m * OUT_FT + lane] = r - mx - logf(ex);
}

extern "C" void kernel_launch(void* const* d_in, const int* in_sizes, int n_in,
                              void* d_out, int out_size, void* d_ws, size_t ws_size,
                              hipStream_t stream) {
    const float* x    = (const float*)d_in[0];
    const int*   esrc = (const int*)  d_in[1];
    const int*   edst = (const int*)  d_in[2];
    const float* ew   = (const float*)d_in[3];
    const float* W1   = (const float*)d_in[4];
    const float* b1   = (const float*)d_in[5];
    const float* W2   = (const float*)d_in[6];
    const float* b2   = (const float*)d_in[7];
    float* out = (float*)d_out;

    // ---- workspace layout ----
    char* p = (char*)d_ws;
    int*  deg    = (int*)p;               p += ((N_NODES     * 4 + 255) & ~255);
    int*  off    = (int*)p;               p += (((N_NODES+1) * 4 + 255) & ~255);
    int*  cursor = (int*)p;               p += ((N_NODES     * 4 + 255) & ~255);
    int2* pk     = (int2*)p;              p += ((size_t)N_EDGES * 8);
    unsigned short* w1t  = (unsigned short*)p;  p += (size_t)H_FT * IN_FT * 2;
    unsigned short* sup1 = (unsigned short*)p;  p += (size_t)N_NODES * H_FT * 2;
    unsigned short* hb   = (unsigned short*)p;  p += (size_t)N_NODES * H_FT * 2;
    float* sup2 = (float*)p;              p += (size_t)N_NODES * OUT_FT * 4;

    hipMemsetAsync(deg, 0, (size_t)N_NODES * 4, stream);

    // CSR build + W1 transpose/convert
    count_k  <<<(N_EDGES + 255) / 256, 256, 0, stream>>>(edst, deg);
    cvtw1t_k <<<dim3(IN_FT / 64, H_FT / 64), 256, 0, stream>>>(W1, w1t);
    scan_k   <<<1, 1024, 0, stream>>>(deg, off, cursor);
    scatter_k<<<(N_EDGES + 255) / 256, 256, 0, stream>>>(esrc, edst, ew, cursor, pk);

    // layer 1
    gemm1_mfma<<<(N_NODES + 63) / 64, 256, 0, stream>>>(x, w1t, b1, sup1);
    spmm1_g   <<<(N_NODES + 3) / 4, 256, 0, stream>>>(off, pk, sup1, hb);

    // layer 2 (+ fused relu + log_softmax)
    gemm2_k   <<<N_NODES / 4, 256, 0, stream>>>(hb, W2, b2, sup2);
    spmm2lsm_k<<<(N_NODES + 3) / 4, 256, 0, stream>>>(off, pk, sup2, out);
}

// Round 4
// 351.248 us; speedup vs baseline: 8.7860x; 1.5251x over previous
//
#include <hip/hip_runtime.h>
#include <math.h>

#define N_NODES 50000
#define N_EDGES 800000
#define IN_FT   512
#define H_FT    256
#define OUT_FT  40
#define NB_SCAN ((N_NODES + 255) / 256)     // 196 blocks

typedef __attribute__((ext_vector_type(8))) short short8;   // 8 x bf16 (4 VGPR)
typedef __attribute__((ext_vector_type(4))) float f32x4;

__device__ __forceinline__ unsigned short f2b(float f) {    // f32 -> bf16 RNE
    unsigned int u = __float_as_uint(f);
    unsigned int r = (u + 0x7FFFu + ((u >> 16) & 1u)) >> 16;
    return (unsigned short)r;
}
__device__ __forceinline__ float b2f(unsigned short h) {
    return __uint_as_float(((unsigned int)h) << 16);
}

// ================= CSR build (dst-sorted) ===================================
__global__ __launch_bounds__(256) void count_k(const int* __restrict__ dst,
                                               int* __restrict__ deg) {
    const int e = blockIdx.x * 256 + threadIdx.x;
    if (e < N_EDGES) atomicAdd(&deg[dst[e]], 1);
}

// stage 1: per-block sums of 256 degrees
__global__ __launch_bounds__(256) void bsum_k(const int* __restrict__ deg,
                                              int* __restrict__ bsum) {
    const int i = blockIdx.x * 256 + threadIdx.x;
    int v = (i < N_NODES) ? deg[i] : 0;
    #pragma unroll
    for (int o = 32; o; o >>= 1) v += __shfl_down(v, o);
    __shared__ int ws[4];
    if ((threadIdx.x & 63) == 0) ws[threadIdx.x >> 6] = v;
    __syncthreads();
    if (threadIdx.x == 0) bsum[blockIdx.x] = ws[0] + ws[1] + ws[2] + ws[3];
}

// stage 2: single-block scan of NB_SCAN block sums -> exclusive boff
__global__ __launch_bounds__(256) void scanb_k(const int* __restrict__ bsum,
                                               int* __restrict__ boff,
                                               int* __restrict__ off) {
    __shared__ int s[256];
    const int t = threadIdx.x;
    int v = (t < NB_SCAN) ? bsum[t] : 0;
    s[t] = v;
    __syncthreads();
    #pragma unroll
    for (int o = 1; o < 256; o <<= 1) {
        int u = (t >= o) ? s[t - o] : 0;
        __syncthreads();
        s[t] += u;
        __syncthreads();
    }
    boff[t] = s[t] - v;                     // exclusive
    if (t == 0) off[N_NODES] = N_EDGES;     // total is a constant
}

// stage 3: per-block rescan + write off/cursor
__global__ __launch_bounds__(256) void write_k(const int* __restrict__ deg,
                                               const int* __restrict__ boff,
                                               int* __restrict__ off,
                                               int* __restrict__ cursor) {
    __shared__ int s[256];
    const int t = threadIdx.x;
    const int i = blockIdx.x * 256 + t;
    const int v = (i < N_NODES) ? deg[i] : 0;
    s[t] = v;
    __syncthreads();
    #pragma unroll
    for (int o = 1; o < 256; o <<= 1) {
        int u = (t >= o) ? s[t - o] : 0;
        __syncthreads();
        s[t] += u;
        __syncthreads();
    }
    if (i < N_NODES) {
        const int ex = boff[blockIdx.x] + s[t] - v;
        off[i] = ex;
        cursor[i] = ex;
    }
}

__global__ __launch_bounds__(256) void scatter_k(const int* __restrict__ src,
                                                 const int* __restrict__ dst,
                                                 const float* __restrict__ w,
                                                 int* __restrict__ cursor,
                                                 int2* __restrict__ pk) {
    const int e = blockIdx.x * 256 + threadIdx.x;
    if (e < N_EDGES) {
        const int d = dst[e];
        const int pos = atomicAdd(&cursor[d], 1);
        pk[pos] = make_int2(src[e], __float_as_int(w[e]));
    }
}

// ========== W1 [512][256] f32  ->  W1T [256][512] bf16 ======================
__global__ __launch_bounds__(256) void cvtw1t_k(const float* __restrict__ W1,
                                                unsigned short* __restrict__ W1T) {
    __shared__ float tile[64][65];
    const int k0 = blockIdx.x * 64;
    const int n0 = blockIdx.y * 64;
    const int t = threadIdx.x;
    const int r = t >> 2, cg = t & 3;
    #pragma unroll
    for (int i = 0; i < 4; ++i) {
        float4 v = *(const float4*)(W1 + (size_t)(k0 + r) * H_FT + n0 + cg * 16 + i * 4);
        tile[r][cg * 16 + i * 4 + 0] = v.x;
        tile[r][cg * 16 + i * 4 + 1] = v.y;
        tile[r][cg * 16 + i * 4 + 2] = v.z;
        tile[r][cg * 16 + i * 4 + 3] = v.w;
    }
    __syncthreads();
    unsigned short o[16];
    #pragma unroll
    for (int i = 0; i < 16; ++i) o[i] = f2b(tile[cg * 16 + i][r]);
    unsigned short* dst = W1T + (size_t)(n0 + r) * IN_FT + k0 + cg * 16;
    *(short8*)(dst + 0) = *(short8*)&o[0];
    *(short8*)(dst + 8) = *(short8*)&o[8];
}

// ====== W2 [256][40] f32 -> W2T [48][256] bf16 (zero-padded cols 40..47) ====
__global__ __launch_bounds__(256) void cvtw2t_k(const float* __restrict__ W2,
                                                unsigned short* __restrict__ W2T) {
    const int n = blockIdx.x;               // 0..47
    const int k = threadIdx.x;              // 0..255
    W2T[(size_t)n * H_FT + k] = (n < OUT_FT) ? f2b(W2[(size_t)k * OUT_FT + n]) : 0;
}

// ================= GEMM1 (MFMA bf16): sup1[M,256] = x @ W1 + b1 =============
__global__ __launch_bounds__(256) void gemm1_mfma(const float* __restrict__ X,
                                                  const unsigned short* __restrict__ W1T,
                                                  const float* __restrict__ bias,
                                                  unsigned short* __restrict__ C) {
    __shared__ unsigned short As[64][72];
    const int t    = threadIdx.x;
    const int lane = t & 63;
    const int wid  = t >> 6;
    const int m0   = blockIdx.x * 64;
    const int srow = t >> 2;
    const int scg  = t & 3;
    const int arow = m0 + srow;
    const bool aval = arow < N_NODES;
    const int fr = lane & 15;
    const int fq = lane >> 4;

    f32x4 acc[4][4] = {};

    const float* xp = X + (size_t)arow * IN_FT + scg * 16;
    const unsigned short* bp = W1T + (size_t)(wid * 64 + fr) * IN_FT + fq * 8;

    for (int k0 = 0; k0 < IN_FT; k0 += 64) {
        float4 v0, v1, v2, v3;
        if (aval) {
            v0 = *(const float4*)(xp + k0 + 0);
            v1 = *(const float4*)(xp + k0 + 4);
            v2 = *(const float4*)(xp + k0 + 8);
            v3 = *(const float4*)(xp + k0 + 12);
        } else {
            v0 = v1 = v2 = v3 = make_float4(0.f, 0.f, 0.f, 0.f);
        }
        unsigned short h[16];
        h[0]=f2b(v0.x); h[1]=f2b(v0.y); h[2]=f2b(v0.z); h[3]=f2b(v0.w);
        h[4]=f2b(v1.x); h[5]=f2b(v1.y); h[6]=f2b(v1.z); h[7]=f2b(v1.w);
        h[8]=f2b(v2.x); h[9]=f2b(v2.y); h[10]=f2b(v2.z); h[11]=f2b(v2.w);
        h[12]=f2b(v3.x); h[13]=f2b(v3.y); h[14]=f2b(v3.z); h[15]=f2b(v3.w);

        __syncthreads();
        *(short8*)&As[srow][scg * 16 + 0] = *(short8*)&h[0];
        *(short8*)&As[srow][scg * 16 + 8] = *(short8*)&h[8];
        __syncthreads();

        #pragma unroll
        for (int ks = 0; ks < 2; ++ks) {
            short8 a[4], b[4];
            #pragma unroll
            for (int mi = 0; mi < 4; ++mi)
                a[mi] = *(const short8*)&As[mi * 16 + fr][ks * 32 + fq * 8];
            #pragma unroll
            for (int ni = 0; ni < 4; ++ni)
                b[ni] = *(const short8*)(bp + (size_t)ni * 16 * IN_FT + k0 + ks * 32);
            #pragma unroll
            for (int mi = 0; mi < 4; ++mi)
                #pragma unroll
                for (int ni = 0; ni < 4; ++ni)
                    acc[mi][ni] = __builtin_amdgcn_mfma_f32_16x16x32_bf16(
                        a[mi], b[ni], acc[mi][ni], 0, 0, 0);
        }
    }

    #pragma unroll
    for (int ni = 0; ni < 4; ++ni) {
        const int col = wid * 64 + ni * 16 + fr;
        const float bv = bias[col];
        #pragma unroll
        for (int mi = 0; mi < 4; ++mi) {
            #pragma unroll
            for (int j = 0; j < 4; ++j) {
                const int row = m0 + mi * 16 + fq * 4 + j;
                if (row < N_NODES)
                    C[(size_t)row * H_FT + col] = f2b(acc[mi][ni][j] + bv);
            }
        }
    }
}

// ========== SpMM1 gather (bf16): h[m] = relu(sum w_e * sup1[src_e]) =========
__global__ __launch_bounds__(256) void spmm1_g(const int* __restrict__ off,
                                               const int2* __restrict__ pk,
                                               const unsigned short* __restrict__ sup,
                                               unsigned short* __restrict__ hout) {
    const int m = blockIdx.x * 4 + (threadIdx.x >> 6);
    if (m >= N_NODES) return;
    const int lane = threadIdx.x & 63;
    float a0 = 0.f, a1 = 0.f, a2 = 0.f, a3 = 0.f;
    const int b = off[m], e = off[m + 1];
    for (int i = b; i < e; ++i) {
        const int2 p = pk[i];
        const float w = __int_as_float(p.y);
        const ushort4 v = *(const ushort4*)(sup + (size_t)p.x * H_FT + lane * 4);
        a0 += b2f(v.x) * w; a1 += b2f(v.y) * w;
        a2 += b2f(v.z) * w; a3 += b2f(v.w) * w;
    }
    ushort4 r;
    r.x = f2b(fmaxf(a0, 0.f)); r.y = f2b(fmaxf(a1, 0.f));
    r.z = f2b(fmaxf(a2, 0.f)); r.w = f2b(fmaxf(a3, 0.f));
    *(ushort4*)(hout + (size_t)m * H_FT + lane * 4) = r;
}

// ======= GEMM2 (MFMA): sup2[M,40] = hb[M,256] @ W2T' + b2 ===================
// 4 waves/block, wave w owns rows m0+w*16..+15; 3 n-tiles (48 cols, 40 live).
__global__ __launch_bounds__(256) void gemm2_mfma(const unsigned short* __restrict__ hb,
                                                  const unsigned short* __restrict__ W2T,
                                                  const float* __restrict__ b2,
                                                  float* __restrict__ sup2) {
    const int t = threadIdx.x;
    const int lane = t & 63;
    const int wid = t >> 6;
    const int fr = lane & 15;
    const int fq = lane >> 4;
    const int row = blockIdx.x * 64 + wid * 16 + fr;
    const int rl = (row < N_NODES) ? row : (N_NODES - 1);

    f32x4 acc[3] = {};
    const unsigned short* ap = hb + (size_t)rl * H_FT + fq * 8;
    #pragma unroll
    for (int ks = 0; ks < 8; ++ks) {
        const short8 a = *(const short8*)(ap + ks * 32);
        #pragma unroll
        for (int ni = 0; ni < 3; ++ni) {
            const short8 b = *(const short8*)(W2T + (size_t)(ni * 16 + fr) * H_FT + ks * 32 + fq * 8);
            acc[ni] = __builtin_amdgcn_mfma_f32_16x16x32_bf16(a, b, acc[ni], 0, 0, 0);
        }
    }
    #pragma unroll
    for (int ni = 0; ni < 3; ++ni) {
        const int col = ni * 16 + fr;
        if (col >= OUT_FT) continue;
        const float bv = b2[col];
        #pragma unroll
        for (int j = 0; j < 4; ++j) {
            const int r = blockIdx.x * 64 + wid * 16 + fq * 4 + j;
            if (r < N_NODES)
                sup2[(size_t)r * OUT_FT + col] = acc[ni][j] + bv;
        }
    }
}

// ===== SpMM2 + relu + log_softmax fused =====================================
__global__ __launch_bounds__(256) void spmm2lsm_k(const int* __restrict__ off,
                                                  const int2* __restrict__ pk,
                                                  const float* __restrict__ sup2,
                                                  float* __restrict__ out) {
    const int m = blockIdx.x * 4 + (threadIdx.x >> 6);
    if (m >= N_NODES) return;
    const int lane = threadIdx.x & 63;
    const int f = (lane < OUT_FT) ? lane : 0;
    float acc = 0.f;
    const int b = off[m], e = off[m + 1];
    for (int i = b; i < e; ++i) {
        const int2 p = pk[i];
        acc += sup2[(size_t)p.x * OUT_FT + f] * __int_as_float(p.y);
    }
    const bool act = (lane < OUT_FT);
    float r = act ? fmaxf(acc, 0.f) : 0.f;
    float mx = act ? r : -INFINITY;
    #pragma unroll
    for (int o = 32; o; o >>= 1) mx = fmaxf(mx, __shfl_xor(mx, o));
    float ex = act ? expf(r - mx) : 0.f;
    #pragma unroll
    for (int o = 32; o; o >>= 1) ex += __shfl_xor(ex, o);
    if (act) out[(size_t)m * OUT_FT + lane] = r - mx - logf(ex);
}

extern "C" void kernel_launch(void* const* d_in, const int* in_sizes, int n_in,
                              void* d_out, int out_size, void* d_ws, size_t ws_size,
                              hipStream_t stream) {
    const float* x    = (const float*)d_in[0];
    const int*   esrc = (const int*)  d_in[1];
    const int*   edst = (const int*)  d_in[2];
    const float* ew   = (const float*)d_in[3];
    const float* W1   = (const float*)d_in[4];
    const float* b1   = (const float*)d_in[5];
    const float* W2   = (const float*)d_in[6];
    const float* b2   = (const float*)d_in[7];
    float* out = (float*)d_out;

    // ---- workspace layout ----
    char* p = (char*)d_ws;
    int*  deg    = (int*)p;               p += ((N_NODES     * 4 + 255) & ~255);
    int*  off    = (int*)p;               p += (((N_NODES+1) * 4 + 255) & ~255);
    int*  cursor = (int*)p;               p += ((N_NODES     * 4 + 255) & ~255);
    int*  bsum   = (int*)p;               p += ((256 * 4 + 255) & ~255);
    int*  boff   = (int*)p;               p += ((257 * 4 + 255) & ~255);
    int2* pk     = (int2*)p;              p += ((size_t)N_EDGES * 8);
    unsigned short* w1t  = (unsigned short*)p;  p += (size_t)H_FT * IN_FT * 2;
    unsigned short* w2t  = (unsigned short*)p;  p += (size_t)48 * H_FT * 2;
    unsigned short* sup1 = (unsigned short*)p;  p += (size_t)N_NODES * H_FT * 2;
    unsigned short* hb   = (unsigned short*)p;  p += (size_t)N_NODES * H_FT * 2;
    float* sup2 = (float*)p;              p += (size_t)N_NODES * OUT_FT * 4;

    hipMemsetAsync(deg, 0, (size_t)N_NODES * 4, stream);

    // CSR build + weight converts
    count_k  <<<(N_EDGES + 255) / 256, 256, 0, stream>>>(edst, deg);
    bsum_k   <<<NB_SCAN, 256, 0, stream>>>(deg, bsum);
    scanb_k  <<<1, 256, 0, stream>>>(bsum, boff, off);
    write_k  <<<NB_SCAN, 256, 0, stream>>>(deg, boff, off, cursor);
    scatter_k<<<(N_EDGES + 255) / 256, 256, 0, stream>>>(esrc, edst, ew, cursor, pk);
    cvtw1t_k <<<dim3(IN_FT / 64, H_FT / 64), 256, 0, stream>>>(W1, w1t);
    cvtw2t_k <<<48, 256, 0, stream>>>(W2, w2t);

    // layer 1
    gemm1_mfma<<<(N_NODES + 63) / 64, 256, 0, stream>>>(x, w1t, b1, sup1);
    spmm1_g   <<<(N_NODES + 3) / 4, 256, 0, stream>>>(off, pk, sup1, hb);

    // layer 2 (+ fused relu + log_softmax)
    gemm2_mfma<<<(N_NODES + 63) / 64, 256, 0, stream>>>(hb, w2t, b2, sup2);
    spmm2lsm_k<<<(N_NODES + 3) / 4, 256, 0, stream>>>(off, pk, sup2, out);
}

// Round 5
// 275.858 us; speedup vs baseline: 11.1872x; 1.2733x over previous
//
#include <hip/hip_runtime.h>
#include <math.h>

#define N_NODES 50000
#define N_EDGES 800000
#define IN_FT   512
#define H_FT    256
#define OUT_FT  40
#define NB_SCAN ((N_NODES + 255) / 256)     // 196 blocks

typedef __attribute__((ext_vector_type(8))) short short8;   // 8 x bf16 (4 VGPR)
typedef __attribute__((ext_vector_type(4))) float f32x4;

__device__ __forceinline__ unsigned short f2b(float f) {    // f32 -> bf16 RNE
    unsigned int u = __float_as_uint(f);
    unsigned int r = (u + 0x7FFFu + ((u >> 16) & 1u)) >> 16;
    return (unsigned short)r;
}
__device__ __forceinline__ float b2f(unsigned short h) {
    return __uint_as_float(((unsigned int)h) << 16);
}

// ================= CSR build (dst-sorted) ===================================
__global__ __launch_bounds__(256) void count_k(const int* __restrict__ dst,
                                               int* __restrict__ deg) {
    const int e = blockIdx.x * 256 + threadIdx.x;
    if (e < N_EDGES) atomicAdd(&deg[dst[e]], 1);
}

__global__ __launch_bounds__(256) void bsum_k(const int* __restrict__ deg,
                                              int* __restrict__ bsum) {
    const int i = blockIdx.x * 256 + threadIdx.x;
    int v = (i < N_NODES) ? deg[i] : 0;
    #pragma unroll
    for (int o = 32; o; o >>= 1) v += __shfl_down(v, o);
    __shared__ int ws[4];
    if ((threadIdx.x & 63) == 0) ws[threadIdx.x >> 6] = v;
    __syncthreads();
    if (threadIdx.x == 0) bsum[blockIdx.x] = ws[0] + ws[1] + ws[2] + ws[3];
}

__global__ __launch_bounds__(256) void scanb_k(const int* __restrict__ bsum,
                                               int* __restrict__ boff,
                                               int* __restrict__ off) {
    __shared__ int s[256];
    const int t = threadIdx.x;
    int v = (t < NB_SCAN) ? bsum[t] : 0;
    s[t] = v;
    __syncthreads();
    #pragma unroll
    for (int o = 1; o < 256; o <<= 1) {
        int u = (t >= o) ? s[t - o] : 0;
        __syncthreads();
        s[t] += u;
        __syncthreads();
    }
    boff[t] = s[t] - v;
    if (t == 0) off[N_NODES] = N_EDGES;
}

__global__ __launch_bounds__(256) void write_k(const int* __restrict__ deg,
                                               const int* __restrict__ boff,
                                               int* __restrict__ off,
                                               int* __restrict__ cursor) {
    __shared__ int s[256];
    const int t = threadIdx.x;
    const int i = blockIdx.x * 256 + t;
    const int v = (i < N_NODES) ? deg[i] : 0;
    s[t] = v;
    __syncthreads();
    #pragma unroll
    for (int o = 1; o < 256; o <<= 1) {
        int u = (t >= o) ? s[t - o] : 0;
        __syncthreads();
        s[t] += u;
        __syncthreads();
    }
    if (i < N_NODES) {
        const int ex = boff[blockIdx.x] + s[t] - v;
        off[i] = ex;
        cursor[i] = ex;
    }
}

__global__ __launch_bounds__(256) void scatter_k(const int* __restrict__ src,
                                                 const int* __restrict__ dst,
                                                 const float* __restrict__ w,
                                                 int* __restrict__ cursor,
                                                 int2* __restrict__ pk) {
    const int e = blockIdx.x * 256 + threadIdx.x;
    if (e < N_EDGES) {
        const int d = dst[e];
        const int pos = atomicAdd(&cursor[d], 1);
        pk[pos] = make_int2(src[e], __float_as_int(w[e]));
    }
}

// ========== W1 [512][256] f32  ->  W1T [256][512] bf16 ======================
__global__ __launch_bounds__(256) void cvtw1t_k(const float* __restrict__ W1,
                                                unsigned short* __restrict__ W1T) {
    __shared__ float tile[64][65];
    const int k0 = blockIdx.x * 64;
    const int n0 = blockIdx.y * 64;
    const int t = threadIdx.x;
    const int r = t >> 2, cg = t & 3;
    #pragma unroll
    for (int i = 0; i < 4; ++i) {
        float4 v = *(const float4*)(W1 + (size_t)(k0 + r) * H_FT + n0 + cg * 16 + i * 4);
        tile[r][cg * 16 + i * 4 + 0] = v.x;
        tile[r][cg * 16 + i * 4 + 1] = v.y;
        tile[r][cg * 16 + i * 4 + 2] = v.z;
        tile[r][cg * 16 + i * 4 + 3] = v.w;
    }
    __syncthreads();
    unsigned short o[16];
    #pragma unroll
    for (int i = 0; i < 16; ++i) o[i] = f2b(tile[cg * 16 + i][r]);
    unsigned short* dst = W1T + (size_t)(n0 + r) * IN_FT + k0 + cg * 16;
    *(short8*)(dst + 0) = *(short8*)&o[0];
    *(short8*)(dst + 8) = *(short8*)&o[8];
}

// ====== W2 [256][40] f32 -> W2T [48][256] bf16 (zero-padded cols 40..47) ====
__global__ __launch_bounds__(256) void cvtw2t_k(const float* __restrict__ W2,
                                                unsigned short* __restrict__ W2T) {
    const int n = blockIdx.x;
    const int k = threadIdx.x;
    W2T[(size_t)n * H_FT + k] = (n < OUT_FT) ? f2b(W2[(size_t)k * OUT_FT + n]) : 0;
}

// ================= GEMM1 (MFMA bf16, double-buffered) =======================
// sup1[M,256] = x @ W1 + b1.  BM=64, BN=256, BK=64, 4 waves (64-col slices).
__global__ __launch_bounds__(256) void gemm1_mfma(const float* __restrict__ X,
                                                  const unsigned short* __restrict__ W1T,
                                                  const float* __restrict__ bias,
                                                  unsigned short* __restrict__ C) {
    __shared__ unsigned short As[2][64][72];   // 2 x 9KB
    const int t    = threadIdx.x;
    const int lane = t & 63;
    const int wid  = t >> 6;
    const int m0   = blockIdx.x * 64;
    const int srow = t >> 2;
    const int scg  = t & 3;
    const int arow = m0 + srow;
    const bool aval = arow < N_NODES;
    const int fr = lane & 15;
    const int fq = lane >> 4;

    f32x4 acc[4][4] = {};

    const float* xp = X + (size_t)arow * IN_FT + scg * 16;
    const unsigned short* bp = W1T + (size_t)(wid * 64 + fr) * IN_FT + fq * 8;

    // ---- prologue: stage k0=0 into buffer 0 ----
    {
        float4 v0, v1, v2, v3;
        if (aval) {
            v0 = *(const float4*)(xp + 0);
            v1 = *(const float4*)(xp + 4);
            v2 = *(const float4*)(xp + 8);
            v3 = *(const float4*)(xp + 12);
        } else {
            v0 = v1 = v2 = v3 = make_float4(0.f, 0.f, 0.f, 0.f);
        }
        unsigned short h[16];
        h[0]=f2b(v0.x); h[1]=f2b(v0.y); h[2]=f2b(v0.z); h[3]=f2b(v0.w);
        h[4]=f2b(v1.x); h[5]=f2b(v1.y); h[6]=f2b(v1.z); h[7]=f2b(v1.w);
        h[8]=f2b(v2.x); h[9]=f2b(v2.y); h[10]=f2b(v2.z); h[11]=f2b(v2.w);
        h[12]=f2b(v3.x); h[13]=f2b(v3.y); h[14]=f2b(v3.z); h[15]=f2b(v3.w);
        *(short8*)&As[0][srow][scg * 16 + 0] = *(short8*)&h[0];
        *(short8*)&As[0][srow][scg * 16 + 8] = *(short8*)&h[8];
    }
    __syncthreads();

#define GEMM1_STEP(KC, CUR, NXT, MORE)                                          \
    {                                                                           \
        float4 w0, w1, w2, w3;                                                  \
        const bool more_ = (MORE);                                              \
        if (more_) {                                                            \
            if (aval) {                                                         \
                w0 = *(const float4*)(xp + (KC) + 64 + 0);                      \
                w1 = *(const float4*)(xp + (KC) + 64 + 4);                      \
                w2 = *(const float4*)(xp + (KC) + 64 + 8);                      \
                w3 = *(const float4*)(xp + (KC) + 64 + 12);                     \
            } else {                                                            \
                w0 = w1 = w2 = w3 = make_float4(0.f, 0.f, 0.f, 0.f);            \
            }                                                                   \
        }                                                                       \
        short8 bf[2][4];                                                        \
        _Pragma("unroll")                                                       \
        for (int ks = 0; ks < 2; ++ks)                                          \
            _Pragma("unroll")                                                   \
            for (int ni = 0; ni < 4; ++ni)                                      \
                bf[ks][ni] = *(const short8*)(bp + (size_t)ni * 16 * IN_FT +    \
                                              (KC) + ks * 32);                  \
        _Pragma("unroll")                                                       \
        for (int ks = 0; ks < 2; ++ks) {                                        \
            short8 a[4];                                                        \
            _Pragma("unroll")                                                   \
            for (int mi = 0; mi < 4; ++mi)                                      \
                a[mi] = *(const short8*)&As[CUR][mi * 16 + fr][ks * 32 + fq * 8];\
            _Pragma("unroll")                                                   \
            for (int mi = 0; mi < 4; ++mi)                                      \
                _Pragma("unroll")                                               \
                for (int ni = 0; ni < 4; ++ni)                                  \
                    acc[mi][ni] = __builtin_amdgcn_mfma_f32_16x16x32_bf16(      \
                        a[mi], bf[ks][ni], acc[mi][ni], 0, 0, 0);               \
        }                                                                       \
        if (more_) {                                                            \
            unsigned short h[16];                                               \
            h[0]=f2b(w0.x); h[1]=f2b(w0.y); h[2]=f2b(w0.z); h[3]=f2b(w0.w);     \
            h[4]=f2b(w1.x); h[5]=f2b(w1.y); h[6]=f2b(w1.z); h[7]=f2b(w1.w);     \
            h[8]=f2b(w2.x); h[9]=f2b(w2.y); h[10]=f2b(w2.z); h[11]=f2b(w2.w);   \
            h[12]=f2b(w3.x); h[13]=f2b(w3.y); h[14]=f2b(w3.z); h[15]=f2b(w3.w); \
            *(short8*)&As[NXT][srow][scg * 16 + 0] = *(short8*)&h[0];           \
            *(short8*)&As[NXT][srow][scg * 16 + 8] = *(short8*)&h[8];           \
        }                                                                       \
        __syncthreads();                                                        \
    }

    #pragma unroll 1
    for (int k0 = 0; k0 < IN_FT; k0 += 128) {
        GEMM1_STEP(k0,      0, 1, true);
        GEMM1_STEP(k0 + 64, 1, 0, k0 + 128 < IN_FT);
    }
#undef GEMM1_STEP

    // epilogue: + bias, -> bf16
    #pragma unroll
    for (int ni = 0; ni < 4; ++ni) {
        const int col = wid * 64 + ni * 16 + fr;
        const float bv = bias[col];
        #pragma unroll
        for (int mi = 0; mi < 4; ++mi) {
            #pragma unroll
            for (int j = 0; j < 4; ++j) {
                const int row = m0 + mi * 16 + fq * 4 + j;
                if (row < N_NODES)
                    C[(size_t)row * H_FT + col] = f2b(acc[mi][ni][j] + bv);
            }
        }
    }
}

// ========== SpMM1 gather (bf16, 4-deep unrolled) ============================
__global__ __launch_bounds__(256) void spmm1_g(const int* __restrict__ off,
                                               const int2* __restrict__ pk,
                                               const unsigned short* __restrict__ sup,
                                               unsigned short* __restrict__ hout) {
    const int m = blockIdx.x * 4 + (threadIdx.x >> 6);
    if (m >= N_NODES) return;
    const int lane = threadIdx.x & 63;
    float a0 = 0.f, a1 = 0.f, a2 = 0.f, a3 = 0.f;
    float c0 = 0.f, c1 = 0.f, c2 = 0.f, c3 = 0.f;
    const int b = off[m], e = off[m + 1];
    int i = b;
    for (; i + 4 <= e; i += 4) {
        const int2 p0 = pk[i], p1 = pk[i + 1], p2 = pk[i + 2], p3 = pk[i + 3];
        const ushort4 u0 = *(const ushort4*)(sup + (size_t)p0.x * H_FT + lane * 4);
        const ushort4 u1 = *(const ushort4*)(sup + (size_t)p1.x * H_FT + lane * 4);
        const ushort4 u2 = *(const ushort4*)(sup + (size_t)p2.x * H_FT + lane * 4);
        const ushort4 u3 = *(const ushort4*)(sup + (size_t)p3.x * H_FT + lane * 4);
        const float w0 = __int_as_float(p0.y), w1 = __int_as_float(p1.y);
        const float w2 = __int_as_float(p2.y), w3 = __int_as_float(p3.y);
        a0 += b2f(u0.x) * w0; a1 += b2f(u0.y) * w0; a2 += b2f(u0.z) * w0; a3 += b2f(u0.w) * w0;
        c0 += b2f(u1.x) * w1; c1 += b2f(u1.y) * w1; c2 += b2f(u1.z) * w1; c3 += b2f(u1.w) * w1;
        a0 += b2f(u2.x) * w2; a1 += b2f(u2.y) * w2; a2 += b2f(u2.z) * w2; a3 += b2f(u2.w) * w2;
        c0 += b2f(u3.x) * w3; c1 += b2f(u3.y) * w3; c2 += b2f(u3.z) * w3; c3 += b2f(u3.w) * w3;
    }
    for (; i < e; ++i) {
        const int2 p = pk[i];
        const float w = __int_as_float(p.y);
        const ushort4 v = *(const ushort4*)(sup + (size_t)p.x * H_FT + lane * 4);
        a0 += b2f(v.x) * w; a1 += b2f(v.y) * w;
        a2 += b2f(v.z) * w; a3 += b2f(v.w) * w;
    }
    a0 += c0; a1 += c1; a2 += c2; a3 += c3;
    ushort4 r;
    r.x = f2b(fmaxf(a0, 0.f)); r.y = f2b(fmaxf(a1, 0.f));
    r.z = f2b(fmaxf(a2, 0.f)); r.w = f2b(fmaxf(a3, 0.f));
    *(ushort4*)(hout + (size_t)m * H_FT + lane * 4) = r;
}

// ======= GEMM2 (MFMA): sup2[M,40] = hb[M,256] @ W2T' + b2 ===================
__global__ __launch_bounds__(256) void gemm2_mfma(const unsigned short* __restrict__ hb,
                                                  const unsigned short* __restrict__ W2T,
                                                  const float* __restrict__ b2,
                                                  float* __restrict__ sup2) {
    const int t = threadIdx.x;
    const int lane = t & 63;
    const int wid = t >> 6;
    const int fr = lane & 15;
    const int fq = lane >> 4;
    const int row = blockIdx.x * 64 + wid * 16 + fr;
    const int rl = (row < N_NODES) ? row : (N_NODES - 1);

    f32x4 acc[3] = {};
    const unsigned short* ap = hb + (size_t)rl * H_FT + fq * 8;
    #pragma unroll
    for (int ks = 0; ks < 8; ++ks) {
        const short8 a = *(const short8*)(ap + ks * 32);
        #pragma unroll
        for (int ni = 0; ni < 3; ++ni) {
            const short8 b = *(const short8*)(W2T + (size_t)(ni * 16 + fr) * H_FT + ks * 32 + fq * 8);
            acc[ni] = __builtin_amdgcn_mfma_f32_16x16x32_bf16(a, b, acc[ni], 0, 0, 0);
        }
    }
    #pragma unroll
    for (int ni = 0; ni < 3; ++ni) {
        const int col = ni * 16 + fr;
        if (col >= OUT_FT) continue;
        const float bv = b2[col];
        #pragma unroll
        for (int j = 0; j < 4; ++j) {
            const int r = blockIdx.x * 64 + wid * 16 + fq * 4 + j;
            if (r < N_NODES)
                sup2[(size_t)r * OUT_FT + col] = acc[ni][j] + bv;
        }
    }
}

// ===== SpMM2 + relu + log_softmax fused (4-deep unrolled) ===================
__global__ __launch_bounds__(256) void spmm2lsm_k(const int* __restrict__ off,
                                                  const int2* __restrict__ pk,
                                                  const float* __restrict__ sup2,
                                                  float* __restrict__ out) {
    const int m = blockIdx.x * 4 + (threadIdx.x >> 6);
    if (m >= N_NODES) return;
    const int lane = threadIdx.x & 63;
    const int f = (lane < OUT_FT) ? lane : 0;
    float accA = 0.f, accB = 0.f;
    const int b = off[m], e = off[m + 1];
    int i = b;
    for (; i + 4 <= e; i += 4) {
        const int2 p0 = pk[i], p1 = pk[i + 1], p2 = pk[i + 2], p3 = pk[i + 3];
        const float v0 = sup2[(size_t)p0.x * OUT_FT + f];
        const float v1 = sup2[(size_t)p1.x * OUT_FT + f];
        const float v2 = sup2[(size_t)p2.x * OUT_FT + f];
        const float v3 = sup2[(size_t)p3.x * OUT_FT + f];
        accA += v0 * __int_as_float(p0.y);
        accB += v1 * __int_as_float(p1.y);
        accA += v2 * __int_as_float(p2.y);
        accB += v3 * __int_as_float(p3.y);
    }
    for (; i < e; ++i) {
        const int2 p = pk[i];
        accA += sup2[(size_t)p.x * OUT_FT + f] * __int_as_float(p.y);
    }
    const float acc = accA + accB;
    const bool act = (lane < OUT_FT);
    float r = act ? fmaxf(acc, 0.f) : 0.f;
    float mx = act ? r : -INFINITY;
    #pragma unroll
    for (int o = 32; o; o >>= 1) mx = fmaxf(mx, __shfl_xor(mx, o));
    float ex = act ? expf(r - mx) : 0.f;
    #pragma unroll
    for (int o = 32; o; o >>= 1) ex += __shfl_xor(ex, o);
    if (act) out[(size_t)m * OUT_FT + lane] = r - mx - logf(ex);
}

extern "C" void kernel_launch(void* const* d_in, const int* in_sizes, int n_in,
                              void* d_out, int out_size, void* d_ws, size_t ws_size,
                              hipStream_t stream) {
    const float* x    = (const float*)d_in[0];
    const int*   esrc = (const int*)  d_in[1];
    const int*   edst = (const int*)  d_in[2];
    const float* ew   = (const float*)d_in[3];
    const float* W1   = (const float*)d_in[4];
    const float* b1   = (const float*)d_in[5];
    const float* W2   = (const float*)d_in[6];
    const float* b2   = (const float*)d_in[7];
    float* out = (float*)d_out;

    // ---- workspace layout ----
    char* p = (char*)d_ws;
    int*  deg    = (int*)p;               p += ((N_NODES     * 4 + 255) & ~255);
    int*  off    = (int*)p;               p += (((N_NODES+1) * 4 + 255) & ~255);
    int*  cursor = (int*)p;               p += ((N_NODES     * 4 + 255) & ~255);
    int*  bsum   = (int*)p;               p += ((256 * 4 + 255) & ~255);
    int*  boff   = (int*)p;               p += ((257 * 4 + 255) & ~255);
    int2* pk     = (int2*)p;              p += ((size_t)N_EDGES * 8);
    unsigned short* w1t  = (unsigned short*)p;  p += (size_t)H_FT * IN_FT * 2;
    unsigned short* w2t  = (unsigned short*)p;  p += (size_t)48 * H_FT * 2;
    unsigned short* sup1 = (unsigned short*)p;  p += (size_t)N_NODES * H_FT * 2;
    unsigned short* hb   = (unsigned short*)p;  p += (size_t)N_NODES * H_FT * 2;
    float* sup2 = (float*)p;              p += (size_t)N_NODES * OUT_FT * 4;

    hipMemsetAsync(deg, 0, (size_t)N_NODES * 4, stream);

    // CSR build + weight converts
    count_k  <<<(N_EDGES + 255) / 256, 256, 0, stream>>>(edst, deg);
    bsum_k   <<<NB_SCAN, 256, 0, stream>>>(deg, bsum);
    scanb_k  <<<1, 256, 0, stream>>>(bsum, boff, off);
    write_k  <<<NB_SCAN, 256, 0, stream>>>(deg, boff, off, cursor);
    scatter_k<<<(N_EDGES + 255) / 256, 256, 0, stream>>>(esrc, edst, ew, cursor, pk);
    cvtw1t_k <<<dim3(IN_FT / 64, H_FT / 64), 256, 0, stream>>>(W1, w1t);
    cvtw2t_k <<<48, 256, 0, stream>>>(W2, w2t);

    // layer 1
    gemm1_mfma<<<(N_NODES + 63) / 64, 256, 0, stream>>>(x, w1t, b1, sup1);
    spmm1_g   <<<(N_NODES + 3) / 4, 256, 0, stream>>>(off, pk, sup1, hb);

    // layer 2 (+ fused relu + log_softmax)
    gemm2_mfma<<<(N_NODES + 63) / 64, 256, 0, stream>>>(hb, w2t, b2, sup2);
    spmm2lsm_k<<<(N_NODES + 3) / 4, 256, 0, stream>>>(off, pk, sup2, out);
}